// Round 7
// baseline (136.029 us; speedup 1.0000x reference)
//
#include <hip/hip_runtime.h>
#include <hip/hip_bf16.h>
#include <cstdint>

// Problem constants
#define BROWS 8192
#define DIN   512
#define DH    1024
#define KTOT  1536          // DIN + DH
#define NT    (KTOT / 64)   // 24 K-tiles of 64
// Only gate columns [0,2048) are live: g block [0,1024), i block [1024,2048).
// (reference bug: f_out and o_out both use i_in -> f_in/o_in are dead)

typedef __bf16 bf16x8 __attribute__((ext_vector_type(8)));
typedef __bf16 bf16x4 __attribute__((ext_vector_type(4)));
typedef float  f32x4  __attribute__((ext_vector_type(4)));

__device__ __forceinline__ void load16_to_lds(const void* gptr, void* lptr) {
    __builtin_amdgcn_global_load_lds(
        (const __attribute__((address_space(1))) uint32_t*)gptr,
        (__attribute__((address_space(3))) uint32_t*)lptr,
        16, 0, 0);
}

// ---------- Kernel 1: convert x|h -> bf16 A[8192][1536], PRE-SWIZZLED ----------
// Within each 128B K-chunk of a row, byte offset is XORed with ((row&7)<<4) so
// the GEMM's linear global_load_lds staging lands bank-conflict-free in LDS.
__global__ __launch_bounds__(256) void cvtA_kernel(
    const float* __restrict__ x, const float* __restrict__ h,
    __bf16* __restrict__ A) {
    int t = blockIdx.x * 256 + threadIdx.x;   // 8192*192 threads (16B units)
    int row = t / 192;
    int j = t - row * 192;
    int kg = j * 8;
    const float* src = (kg < DIN) ? (x + (size_t)row * DIN + kg)
                                  : (h + (size_t)row * DH + (kg - DIN));
    float4 u = *(const float4*)src;
    float4 v = *(const float4*)(src + 4);
    bf16x8 o = { (__bf16)u.x, (__bf16)u.y, (__bf16)u.z, (__bf16)u.w,
                 (__bf16)v.x, (__bf16)v.y, (__bf16)v.z, (__bf16)v.w };
    int swz = (j * 16) ^ ((row & 7) << 4);
    *(bf16x8*)((char*)A + (size_t)row * 3072 + swz) = o;
}

// ---------- Kernel 2: transpose+convert W cols [0,2048) -> bf16 Bt[2048][1536] ----------
// PLAIN row-major (no swizzle): B is consumed by direct per-lane global loads.
__global__ __launch_bounds__(256) void cvtB_kernel(
    const float* __restrict__ Wx, const float* __restrict__ Wh,
    __bf16* __restrict__ Bt) {
    __shared__ float tile[32][33];
    int k0 = blockIdx.x * 32;
    int n0 = blockIdx.y * 32;
    int tx = threadIdx.x;   // 0..31
    int ty = threadIdx.y;   // 0..7
#pragma unroll
    for (int i = 0; i < 4; ++i) {
        int k = k0 + ty + 8 * i;
        float v = (k < DIN) ? Wx[(size_t)k * 4096 + n0 + tx]
                            : Wh[(size_t)(k - DIN) * 4096 + n0 + tx];
        tile[ty + 8 * i][tx] = v;
    }
    __syncthreads();
    int n = n0 + tx;
    int kk = ty * 4;
    bf16x4 o = { (__bf16)tile[kk][tx], (__bf16)tile[kk + 1][tx],
                 (__bf16)tile[kk + 2][tx], (__bf16)tile[kk + 3][tx] };
    *(bf16x4*)(Bt + (size_t)n * KTOT + k0 + kk) = o;
}

// ---------- Kernel 3: GEMM, A via LDS (dbuf), B direct from L2 into regs ----------
// Block 128(M) x 64(n'), 256 threads = 4 waves (2M x 2N); wave = 64M x 32n' x {g,i}.
// LDS = A only, 2 x 128 x 64 bf16 = 32 KiB -> 3 blocks/CU (VGPR-capped 3 w/SIMD).
// One barrier per K-tile. Per-tile VMEM queue: [Bg x4][Bi x4][As(t+1) x4].
//   VMW(8) -> As(t) landed (then barrier); VMW(8) -> Bg landed; VMW(4) -> Bi.

#define BARRIER  do { __builtin_amdgcn_sched_barrier(0); __builtin_amdgcn_s_barrier(); __builtin_amdgcn_sched_barrier(0); } while (0)
#define VMW(n)   do { asm volatile("s_waitcnt vmcnt(" #n ")" ::: "memory"); __builtin_amdgcn_sched_barrier(0); } while (0)
#define LGKM0    do { asm volatile("s_waitcnt lgkmcnt(0)" ::: "memory"); __builtin_amdgcn_sched_barrier(0); } while (0)

#define STAGE_A(buf, kt) do {                                                  \
    _Pragma("unroll")                                                          \
    for (int p_ = 0; p_ < 4; ++p_) {                                           \
        const char* g_ = Ab + (size_t)(brow + p_ * 32 + r0) * 3072             \
                            + (size_t)(kt) * 128 + cb;                         \
        load16_to_lds(g_, sAb + (buf) * 16384 + (p_ * 32 + r0) * 128 + cb);    \
    }                                                                          \
    __builtin_amdgcn_sched_barrier(0);                                         \
} while (0)

#define READ_A(c)                                                              \
    _Pragma("unroll")                                                          \
    for (int m_ = 0; m_ < 4; ++m_) {                                           \
        _Pragma("unroll")                                                      \
        for (int ks_ = 0; ks_ < 2; ++ks_) {                                    \
            int row_ = wrow + m_ * 16 + l15;                                   \
            int kb_ = ks_ * 64 + l4x16;                                        \
            aF[m_][ks_] = *(const bf16x8*)(sAb + (c) * 16384 + row_ * 128      \
                                           + (kb_ ^ swzkey));                  \
        }                                                                      \
    }

#define LOAD_B(dst, rowbase, kt) do {                                          \
    _Pragma("unroll")                                                          \
    for (int ni_ = 0; ni_ < 2; ++ni_) {                                        \
        _Pragma("unroll")                                                      \
        for (int ks_ = 0; ks_ < 2; ++ks_) {                                    \
            dst[ni_][ks_] = *(const bf16x8*)(Bt                                \
                + (size_t)((rowbase) + ni_ * 16) * KTOT                        \
                + (kt) * 64 + ks_ * 32 + l4x8);                                \
        }                                                                      \
    }                                                                          \
    __builtin_amdgcn_sched_barrier(0);                                         \
} while (0)

#define MMA(ACC, AF, BF) do {                                                  \
    __builtin_amdgcn_s_setprio(1);                                             \
    _Pragma("unroll")                                                          \
    for (int ks_ = 0; ks_ < 2; ++ks_) {                                        \
        _Pragma("unroll")                                                      \
        for (int m_ = 0; m_ < 4; ++m_) {                                       \
            _Pragma("unroll")                                                  \
            for (int ni_ = 0; ni_ < 2; ++ni_) {                                \
                ACC[m_][ni_] = __builtin_amdgcn_mfma_f32_16x16x32_bf16(        \
                    AF[m_][ks_], BF[ni_][ks_], ACC[m_][ni_], 0, 0, 0);         \
            }                                                                  \
        }                                                                      \
    }                                                                          \
    __builtin_amdgcn_s_setprio(0);                                             \
    __builtin_amdgcn_sched_barrier(0);                                         \
} while (0)

__global__ __launch_bounds__(256, 3) void lstm_gemm_kernel(
    const __bf16* __restrict__ A,    // [8192][1536] pre-swizzled
    const __bf16* __restrict__ Bt,   // [2048][1536] plain row-major
    const float* __restrict__ bias,  // [4096]
    const float* __restrict__ c_in,  // [8192][1024]
    float* __restrict__ out_h,       // [8192][1024]
    float* __restrict__ out_c) {     // [8192][1024]
    __shared__ __bf16 sA[2][128][64];   // 32 KiB, double-buffered A tile

    const int tid  = threadIdx.x;
    const int lane = tid & 63;
    const int wid  = tid >> 6;
    const int wr   = wid & 1;          // 2 wave-rows (M)
    const int wc   = wid >> 1;         // 2 wave-cols (N)

    // Region map: 16 regions (16 bands x 4 panels each); region = bid mod 16
    // so XCD x (= bid mod 8) serves panel-group (x & 3): B slice/XCD = 1.5 MB.
    const int bid   = blockIdx.x;          // 0..1023
    const int rg    = bid & 15;
    const int m     = bid >> 4;            // 0..63
    const int band  = (rg >> 2) * 16 + (m & 15);   // 0..63
    const int panel = (rg & 3) * 4 + (m >> 4);     // 0..15
    const int brow  = band * 128;
    const int bnp   = panel * 64;

    const int l15    = lane & 15;
    const int l4x16  = (lane >> 4) * 16;   // byte k-offset within 128B row
    const int l4x8   = (lane >> 4) * 8;    // element k-offset for B loads
    const int swzkey = (l15 & 7) << 4;
    const int wrow   = wr * 64;

    // staging lane mapping: LDS dst = wave-uniform base + lane*16
    const int r0 = tid >> 3;           // 0..31
    const int cb = (tid & 7) * 16;     // 0..112

    const int rowg = bnp + wc * 32 + l15;          // g-gate B row
    const int rowi = 1024 + rowg;                  // i-gate B row

    const char* Ab = (const char*)A;
    char* sAb = (char*)&sA[0][0][0];

    f32x4 accg[4][2], acci[4][2];
#pragma unroll
    for (int mi = 0; mi < 4; ++mi)
#pragma unroll
        for (int ni = 0; ni < 2; ++ni) {
            accg[mi][ni] = (f32x4){0.f, 0.f, 0.f, 0.f};
            acci[mi][ni] = (f32x4){0.f, 0.f, 0.f, 0.f};
        }

    bf16x8 aF[4][2], bgF[2][2], biF[2][2];

    STAGE_A(0, 0);                       // prologue: As(0) -> buf 0

    for (int t = 0; t < NT - 1; ++t) {
        const int c  = t & 1;
        const int nb = c ^ 1;
        LOAD_B(bgF, rowg, t);            // 4 vmem (regs)
        LOAD_B(biF, rowi, t);            // 4 vmem (regs)
        VMW(8);                          // As(t) landed (own wave's)
        BARRIER;                         // all waves' As(t) landed
        READ_A(c);                       // 8 ds_read_b128
        STAGE_A(nb, t + 1);              // 4 vmem -> other buffer
        LGKM0;                           // aF ready
        VMW(8);                          // Bg landed
        MMA(accg, aF, bgF);
        VMW(4);                          // Bi landed
        MMA(acci, aF, biF);
    }
    {   // last tile: no prefetch; drains 8 -> 4 -> 0
        const int c = (NT - 1) & 1;
        LOAD_B(bgF, rowg, NT - 1);
        LOAD_B(biF, rowi, NT - 1);
        VMW(8);                          // As(NT-1) landed
        BARRIER;
        READ_A(c);
        LGKM0;
        VMW(4);                          // Bg landed
        MMA(accg, aF, bgF);
        VMW(0);                          // Bi landed
        MMA(acci, aF, biF);
    }

    // Epilogue: s = sigmoid(i_in); t = tanh(g_in); c_new = s*(t+c); h_new = tanh(c_new)*s
    const int R0 = brow + wrow;
    const int C0 = bnp + wc * 32;
    const int l4 = lane >> 4;
#pragma unroll
    for (int ni = 0; ni < 2; ++ni) {
        const int col = C0 + ni * 16 + l15;
        const float bg = bias[col];
        const float bi = bias[1024 + col];
#pragma unroll
        for (int mi = 0; mi < 4; ++mi) {
#pragma unroll
            for (int r = 0; r < 4; ++r) {
                const int row = R0 + mi * 16 + l4 * 4 + r;
                const float g_in = accg[mi][ni][r] + bg;
                const float i_in = acci[mi][ni][r] + bi;
                const float s  = 1.0f / (1.0f + __expf(-i_in));
                const float tg = 2.0f / (1.0f + __expf(-2.0f * g_in)) - 1.0f;
                const float cv = c_in[(size_t)row * DH + col];
                const float cn = s * (tg + cv);
                const float hn = (2.0f / (1.0f + __expf(-2.0f * cn)) - 1.0f) * s;
                out_h[(size_t)row * DH + col] = hn;
                out_c[(size_t)row * DH + col] = cn;
            }
        }
    }
}

extern "C" void kernel_launch(void* const* d_in, const int* in_sizes, int n_in,
                              void* d_out, int out_size, void* d_ws, size_t ws_size,
                              hipStream_t stream) {
    const float* x  = (const float*)d_in[0];
    const float* h  = (const float*)d_in[1];
    const float* c  = (const float*)d_in[2];
    const float* Wx = (const float*)d_in[3];
    const float* Wh = (const float*)d_in[4];
    const float* b  = (const float*)d_in[5];

    __bf16* A  = (__bf16*)d_ws;                                     // 25,165,824 B
    __bf16* Bt = (__bf16*)((char*)d_ws + (size_t)BROWS * KTOT * 2); // 6,291,456 B

    float* out_h = (float*)d_out;
    float* out_c = out_h + (size_t)BROWS * DH;

    cvtA_kernel<<<(BROWS * (KTOT / 8)) / 256, 256, 0, stream>>>(x, h, A);
    cvtB_kernel<<<dim3(KTOT / 32, 2048 / 32), dim3(32, 8), 0, stream>>>(Wx, Wh, Bt);
    lstm_gemm_kernel<<<1024, 256, 0, stream>>>(A, Bt, b, c, out_h, out_c);
}

// Round 8
// 88.102 us; speedup vs baseline: 1.5440x; 1.5440x over previous
//
#include <hip/hip_runtime.h>
#include <hip/hip_bf16.h>
#include <cstdint>

// Problem constants
#define BROWS 8192
#define DIN   512
#define DH    1024
#define KTOT  1536          // DIN + DH
#define NT    (KTOT / 64)   // 24 K-tiles of 64
// Only gate columns [0,2048) are live: g block [0,1024), i block [1024,2048).
// (reference bug: f_out and o_out both use i_in -> f_in/o_in are dead)

typedef __bf16 bf16x8 __attribute__((ext_vector_type(8)));
typedef __bf16 bf16x4 __attribute__((ext_vector_type(4)));
typedef float  f32x4  __attribute__((ext_vector_type(4)));

__device__ __forceinline__ void load16_to_lds(const void* gptr, void* lptr) {
    __builtin_amdgcn_global_load_lds(
        (const __attribute__((address_space(1))) uint32_t*)gptr,
        (__attribute__((address_space(3))) uint32_t*)lptr,
        16, 0, 0);
}

// ---------- Kernel 1: convert x|h -> bf16 A[8192][1536], PRE-SWIZZLED ----------
// Within each 128B K-chunk of a row, byte offset is XORed with ((row&7)<<4) so
// the GEMM's linear global_load_lds staging lands bank-conflict-free in LDS.
__global__ __launch_bounds__(256) void cvtA_kernel(
    const float* __restrict__ x, const float* __restrict__ h,
    __bf16* __restrict__ A) {
    int t = blockIdx.x * 256 + threadIdx.x;   // 8192*192 threads (16B units)
    int row = t / 192;
    int j = t - row * 192;
    int kg = j * 8;
    const float* src = (kg < DIN) ? (x + (size_t)row * DIN + kg)
                                  : (h + (size_t)row * DH + (kg - DIN));
    float4 u = *(const float4*)src;
    float4 v = *(const float4*)(src + 4);
    bf16x8 o = { (__bf16)u.x, (__bf16)u.y, (__bf16)u.z, (__bf16)u.w,
                 (__bf16)v.x, (__bf16)v.y, (__bf16)v.z, (__bf16)v.w };
    int swz = (j * 16) ^ ((row & 7) << 4);
    *(bf16x8*)((char*)A + (size_t)row * 3072 + swz) = o;
}

// ---------- Kernel 2: transpose+convert W cols [0,2048) -> FRAGMENT-MAJOR Bf ----------
// Bf is stored as 1 KB MFMA B-fragments: frag (fr, kc) covers gate-cols
// [fr*16, fr*16+16) x K [kc*32, kc*32+32). Within a frag, lane l's 16 B hold
// B[k = (l>>4)*8 + j][col = l&15] for j=0..7 -> a wave reads one frag as a
// single fully-coalesced global_load_dwordx4 at (base + lane*16).
__global__ __launch_bounds__(256) void cvtB_kernel(
    const float* __restrict__ Wx, const float* __restrict__ Wh,
    __bf16* __restrict__ Bf) {
    __shared__ float tile[32][33];
    int k0 = blockIdx.x * 32;
    int n0 = blockIdx.y * 32;
    int tx = threadIdx.x;   // 0..31
    int ty = threadIdx.y;   // 0..7
#pragma unroll
    for (int i = 0; i < 4; ++i) {
        int k = k0 + ty + 8 * i;
        float v = (k < DIN) ? Wx[(size_t)k * 4096 + n0 + tx]
                            : Wh[(size_t)(k - DIN) * 4096 + n0 + tx];
        tile[ty + 8 * i][tx] = v;
    }
    __syncthreads();
    int n  = n0 + tx;          // gate-col 0..2047
    int kk = ty * 4;           // k-local 0..28
    bf16x4 o = { (__bf16)tile[kk][tx], (__bf16)tile[kk + 1][tx],
                 (__bf16)tile[kk + 2][tx], (__bf16)tile[kk + 3][tx] };
    int fr   = n >> 4;                         // frag row 0..127
    int kc   = k0 >> 5;                        // k-chunk 0..47
    int lane = (n & 15) + (ty >> 1) * 16;      // lane within frag
    int j0   = (ty & 1) * 4;                   // j offset within lane's 8
    size_t elem = (((size_t)fr * 48 + kc) << 9) + lane * 8 + j0;
    *(bf16x4*)(Bf + elem) = o;
}

// ---------- Kernel 3: GEMM, A via LDS (dbuf), B via coalesced frag loads ----------
// Block 128(M) x 64(n'), 256 threads = 4 waves (2M x 2N'); wave = 64M x 32n' x {g,i}.
// LDS = A only, 2 x 128 x 64 bf16 = 32 KiB; ~150 VGPR -> 3 blocks/CU.
// Per block-K-tile: LDS reads 16 b128 (4 waves x ... = 384 cy) < MFMA (620 cy).
// One barrier per K-tile. Per-tile VMEM queue: [Bg x4][Bi x4][As(t+1) x4]:
//   VMW(8) -> As(t) landed (then barrier); VMW(8) -> Bg landed; VMW(4) -> Bi.

#define BARRIER  do { __builtin_amdgcn_sched_barrier(0); __builtin_amdgcn_s_barrier(); __builtin_amdgcn_sched_barrier(0); } while (0)
#define VMW(n)   do { asm volatile("s_waitcnt vmcnt(" #n ")" ::: "memory"); __builtin_amdgcn_sched_barrier(0); } while (0)
#define LGKM0    do { asm volatile("s_waitcnt lgkmcnt(0)" ::: "memory"); __builtin_amdgcn_sched_barrier(0); } while (0)

#define STAGE_A(buf, kt) do {                                                  \
    _Pragma("unroll")                                                          \
    for (int p_ = 0; p_ < 4; ++p_) {                                           \
        const char* g_ = Ab + (size_t)(brow + p_ * 32 + r0) * 3072             \
                            + (size_t)(kt) * 128 + cb;                         \
        load16_to_lds(g_, sAb + (buf) * 16384 + (p_ * 32 + r0) * 128 + cb);    \
    }                                                                          \
    __builtin_amdgcn_sched_barrier(0);                                         \
} while (0)

#define READ_A(c)                                                              \
    _Pragma("unroll")                                                          \
    for (int m_ = 0; m_ < 4; ++m_) {                                           \
        _Pragma("unroll")                                                      \
        for (int ks_ = 0; ks_ < 2; ++ks_) {                                    \
            int row_ = wrow + m_ * 16 + l15;                                   \
            int kb_ = ks_ * 64 + l4x16;                                        \
            aF[m_][ks_] = *(const bf16x8*)(sAb + (c) * 16384 + row_ * 128      \
                                           + (kb_ ^ swzkey));                  \
        }                                                                      \
    }

#define LOAD_B(dst, frbase, kt) do {                                           \
    _Pragma("unroll")                                                          \
    for (int ni_ = 0; ni_ < 2; ++ni_) {                                        \
        _Pragma("unroll")                                                      \
        for (int ks_ = 0; ks_ < 2; ++ks_) {                                    \
            dst[ni_][ks_] = *(const bf16x8*)(Bf                                \
                + ((((size_t)((frbase) + ni_) * 48) + (kt) * 2 + ks_) << 9)    \
                + (lane << 3));                                                \
        }                                                                      \
    }                                                                          \
    __builtin_amdgcn_sched_barrier(0);                                         \
} while (0)

#define MMA(ACC, AF, BF) do {                                                  \
    __builtin_amdgcn_s_setprio(1);                                             \
    _Pragma("unroll")                                                          \
    for (int ks_ = 0; ks_ < 2; ++ks_) {                                        \
        _Pragma("unroll")                                                      \
        for (int m_ = 0; m_ < 4; ++m_) {                                       \
            _Pragma("unroll")                                                  \
            for (int ni_ = 0; ni_ < 2; ++ni_) {                                \
                ACC[m_][ni_] = __builtin_amdgcn_mfma_f32_16x16x32_bf16(        \
                    AF[m_][ks_], BF[ni_][ks_], ACC[m_][ni_], 0, 0, 0);         \
            }                                                                  \
        }                                                                      \
    }                                                                          \
    __builtin_amdgcn_s_setprio(0);                                             \
    __builtin_amdgcn_sched_barrier(0);                                         \
} while (0)

__global__ __launch_bounds__(256, 3) void lstm_gemm_kernel(
    const __bf16* __restrict__ A,    // [8192][1536] pre-swizzled
    const __bf16* __restrict__ Bf,   // fragment-major B (128 fr x 48 kc x 1KB)
    const float* __restrict__ bias,  // [4096]
    const float* __restrict__ c_in,  // [8192][1024]
    float* __restrict__ out_h,       // [8192][1024]
    float* __restrict__ out_c) {     // [8192][1024]
    __shared__ __bf16 sA[2][128][64];   // 32 KiB, double-buffered A tile

    const int tid  = threadIdx.x;
    const int lane = tid & 63;
    const int wid  = tid >> 6;
    const int wr   = wid & 1;          // 2 wave-rows (M)
    const int wc   = wid >> 1;         // 2 wave-cols (n')

    // L2-friendly map (R5-proven, tightened to 4-band sub-sweeps):
    // XCD x serves bands [x*8, x*8+8) in two 4-band halves; within a half,
    // band is fast over 4 (A ws 1.6 MB) and panel advances every 4 blocks
    // (B panel slice 0.4 MB stays L2-resident). A fetched once per XCD.
    const int bid   = blockIdx.x;          // 0..1023
    const int xcd   = bid & 7;
    const int q     = bid >> 3;            // 0..127
    const int band  = xcd * 8 + ((q >> 6) & 1) * 4 + (q & 3);  // 0..63
    const int panel = (q >> 2) & 15;       // 0..15
    const int brow  = band * 128;
    const int bnp   = panel * 64;

    const int l15    = lane & 15;
    const int l4x16  = (lane >> 4) * 16;   // byte k-offset within 128B row
    const int swzkey = (l15 & 7) << 4;
    const int wrow   = wr * 64;

    // staging lane mapping: LDS dst = wave-uniform base + lane*16
    const int r0 = tid >> 3;           // 0..31
    const int cb = (tid & 7) * 16;     // 0..112

    const int frg = (bnp >> 4) + wc * 2;   // g-gate frag-row base (0..62)
    const int fri = 64 + frg;              // i-gate frag-row base

    const char* Ab = (const char*)A;
    char* sAb = (char*)&sA[0][0][0];

    f32x4 accg[4][2], acci[4][2];
#pragma unroll
    for (int mi = 0; mi < 4; ++mi)
#pragma unroll
        for (int ni = 0; ni < 2; ++ni) {
            accg[mi][ni] = (f32x4){0.f, 0.f, 0.f, 0.f};
            acci[mi][ni] = (f32x4){0.f, 0.f, 0.f, 0.f};
        }

    bf16x8 aF[4][2], bgF[2][2], biF[2][2];

    STAGE_A(0, 0);                       // prologue: As(0) -> buf 0

    for (int t = 0; t < NT - 1; ++t) {
        const int c  = t & 1;
        const int nb = c ^ 1;
        LOAD_B(bgF, frg, t);             // 4 coalesced vmem -> regs
        LOAD_B(biF, fri, t);             // 4 coalesced vmem -> regs
        VMW(8);                          // As(t) landed (own wave's)
        BARRIER;                         // all waves' As(t) in LDS
        READ_A(c);                       // 8 ds_read_b128
        STAGE_A(nb, t + 1);              // 4 vmem -> other buffer
        LGKM0;                           // aF ready
        VMW(8);                          // Bg landed
        MMA(accg, aF, bgF);
        VMW(4);                          // Bi landed
        MMA(acci, aF, biF);
    }
    {   // last tile: no prefetch; drains 8 -> 4 -> 0
        const int c = (NT - 1) & 1;
        LOAD_B(bgF, frg, NT - 1);
        LOAD_B(biF, fri, NT - 1);
        VMW(8);                          // As(NT-1) landed
        BARRIER;
        READ_A(c);
        LGKM0;
        VMW(4);                          // Bg landed
        MMA(accg, aF, bgF);
        VMW(0);                          // Bi landed
        MMA(acci, aF, biF);
    }

    // Epilogue: s = sigmoid(i_in); t = tanh(g_in); c_new = s*(t+c); h_new = tanh(c_new)*s
    const int R0 = brow + wrow;
    const int C0 = bnp + wc * 32;
    const int l4 = lane >> 4;
#pragma unroll
    for (int ni = 0; ni < 2; ++ni) {
        const int col = C0 + ni * 16 + l15;
        const float bg = bias[col];
        const float bi = bias[1024 + col];
#pragma unroll
        for (int mi = 0; mi < 4; ++mi) {
#pragma unroll
            for (int r = 0; r < 4; ++r) {
                const int row = R0 + mi * 16 + l4 * 4 + r;
                const float g_in = accg[mi][ni][r] + bg;
                const float i_in = acci[mi][ni][r] + bi;
                const float s  = 1.0f / (1.0f + __expf(-i_in));
                const float tg = 2.0f / (1.0f + __expf(-2.0f * g_in)) - 1.0f;
                const float cv = c_in[(size_t)row * DH + col];
                const float cn = s * (tg + cv);
                const float hn = (2.0f / (1.0f + __expf(-2.0f * cn)) - 1.0f) * s;
                out_h[(size_t)row * DH + col] = hn;
                out_c[(size_t)row * DH + col] = cn;
            }
        }
    }
}

extern "C" void kernel_launch(void* const* d_in, const int* in_sizes, int n_in,
                              void* d_out, int out_size, void* d_ws, size_t ws_size,
                              hipStream_t stream) {
    const float* x  = (const float*)d_in[0];
    const float* h  = (const float*)d_in[1];
    const float* c  = (const float*)d_in[2];
    const float* Wx = (const float*)d_in[3];
    const float* Wh = (const float*)d_in[4];
    const float* b  = (const float*)d_in[5];

    __bf16* A  = (__bf16*)d_ws;                                     // 25,165,824 B
    __bf16* Bf = (__bf16*)((char*)d_ws + (size_t)BROWS * KTOT * 2); // 6,291,456 B

    float* out_h = (float*)d_out;
    float* out_c = out_h + (size_t)BROWS * DH;

    cvtA_kernel<<<(BROWS * (KTOT / 8)) / 256, 256, 0, stream>>>(x, h, A);
    cvtB_kernel<<<dim3(KTOT / 32, 2048 / 32), dim3(32, 8), 0, stream>>>(Wx, Wh, Bf);
    lstm_gemm_kernel<<<1024, 256, 0, stream>>>(A, Bf, b, c, out_h, out_c);
}

// Round 9
// 81.910 us; speedup vs baseline: 1.6607x; 1.0756x over previous
//
#include <hip/hip_runtime.h>
#include <hip/hip_bf16.h>
#include <cstdint>

// Problem constants
#define BROWS 8192
#define DIN   512
#define DH    1024
#define KTOT  1536          // DIN + DH
#define NT    (KTOT / 64)   // 24 K-tiles of 64
// Only gate columns [0,2048) are live: g block [0,1024), i block [1024,2048).
// (reference bug: f_out and o_out both use i_in -> f_in/o_in are dead)

typedef __bf16 bf16x8 __attribute__((ext_vector_type(8)));
typedef __bf16 bf16x4 __attribute__((ext_vector_type(4)));
typedef float  f32x4  __attribute__((ext_vector_type(4)));

__device__ __forceinline__ void load16_to_lds(const void* gptr, void* lptr) {
    __builtin_amdgcn_global_load_lds(
        (const __attribute__((address_space(1))) uint32_t*)gptr,
        (__attribute__((address_space(3))) uint32_t*)lptr,
        16, 0, 0);
}

// ---------- Kernel 1: convert x|h -> bf16 A[8192][1536], PRE-SWIZZLED ----------
// Within each 128B K-chunk of a row, byte offset is XORed with ((row&7)<<4) so
// the GEMM's linear global_load_lds staging lands bank-conflict-free in LDS.
__global__ __launch_bounds__(256) void cvtA_kernel(
    const float* __restrict__ x, const float* __restrict__ h,
    __bf16* __restrict__ A) {
    int t = blockIdx.x * 256 + threadIdx.x;   // 8192*192 threads (16B units)
    int row = t / 192;
    int j = t - row * 192;
    int kg = j * 8;
    const float* src = (kg < DIN) ? (x + (size_t)row * DIN + kg)
                                  : (h + (size_t)row * DH + (kg - DIN));
    float4 u = *(const float4*)src;
    float4 v = *(const float4*)(src + 4);
    bf16x8 o = { (__bf16)u.x, (__bf16)u.y, (__bf16)u.z, (__bf16)u.w,
                 (__bf16)v.x, (__bf16)v.y, (__bf16)v.z, (__bf16)v.w };
    int swz = (j * 16) ^ ((row & 7) << 4);
    *(bf16x8*)((char*)A + (size_t)row * 3072 + swz) = o;
}

// ---------- Kernel 2: transpose+convert W cols [0,2048) -> bf16 Bt[2048][1536], PRE-SWIZZLED ----------
__global__ __launch_bounds__(256) void cvtB_kernel(
    const float* __restrict__ Wx, const float* __restrict__ Wh,
    __bf16* __restrict__ Bt) {
    __shared__ float tile[32][33];
    int k0 = blockIdx.x * 32;
    int n0 = blockIdx.y * 32;
    int tx = threadIdx.x;   // 0..31
    int ty = threadIdx.y;   // 0..7
#pragma unroll
    for (int i = 0; i < 4; ++i) {
        int k = k0 + ty + 8 * i;
        float v = (k < DIN) ? Wx[(size_t)k * 4096 + n0 + tx]
                            : Wh[(size_t)(k - DIN) * 4096 + n0 + tx];
        tile[ty + 8 * i][tx] = v;
    }
    __syncthreads();
    int n = n0 + tx;
    int kk = ty * 4;
    bf16x4 o = { (__bf16)tile[kk][tx], (__bf16)tile[kk + 1][tx],
                 (__bf16)tile[kk + 2][tx], (__bf16)tile[kk + 3][tx] };
    int swz = ((k0 + kk) * 2) ^ ((n & 7) << 4);
    *(bf16x4*)((char*)Bt + (size_t)n * 3072 + swz) = o;
}

// ---------- Kernel 3: 8-phase double-buffered GEMM + fused LSTM epilogue ----------
// Tile 256(M) x 128(n'), B-tile = g-panel(128 rows) + i-panel(128 rows).
// 8 waves = 4(M) x 2(N); waves are M-parallel, so EVERY phase that reads A
// fragments touches BOTH A half-tiles. Therefore stage order is A0, A1, Bg, Bi
// and P1 waits vmcnt(2) (A0+A1+Bg landed); P3 waits vmcnt(4) (Bi landed).

#define BARRIER  do { __builtin_amdgcn_sched_barrier(0); __builtin_amdgcn_s_barrier(); __builtin_amdgcn_sched_barrier(0); } while (0)
#define VMW(n)   do { asm volatile("s_waitcnt vmcnt(" #n ")" ::: "memory"); __builtin_amdgcn_sched_barrier(0); } while (0)
#define LGKM0    do { asm volatile("s_waitcnt lgkmcnt(0)" ::: "memory"); __builtin_amdgcn_sched_barrier(0); } while (0)

#define STAGE_A(buf, mh, kt) do {                                              \
    const char* g0_ = Ab + (size_t)(brow + (mh) * 128 + r0) * 3072             \
                         + (size_t)(kt) * 128 + cb;                            \
    char* l0_ = sAb + (buf) * 32768 + ((mh) * 128 + r0) * 128 + cb;            \
    load16_to_lds(g0_, l0_);                                                   \
    load16_to_lds(g0_ + 64 * 3072, l0_ + 64 * 128);                            \
} while (0)

#define STAGE_B(buf, half, kt) do {                                            \
    const char* g0_ = Bb + (size_t)((half) * 1024 + bnp + r0) * 3072           \
                         + (size_t)(kt) * 128 + cb;                            \
    char* l0_ = sBb + (buf) * 32768 + ((half) * 128 + r0) * 128 + cb;          \
    load16_to_lds(g0_, l0_);                                                   \
    load16_to_lds(g0_ + 64 * 3072, l0_ + 64 * 128);                            \
} while (0)

#define READ_A(dst, c, mh)                                                     \
    _Pragma("unroll")                                                          \
    for (int m2_ = 0; m2_ < 2; ++m2_) {                                        \
        _Pragma("unroll")                                                      \
        for (int ks_ = 0; ks_ < 2; ++ks_) {                                    \
            int row_ = wrow + (mh) * 32 + m2_ * 16 + l15;                      \
            int kb_ = ks_ * 64 + l4x16;                                        \
            dst[m2_][ks_] = *(const bf16x8*)(sAb + (c) * 32768 + row_ * 128    \
                                             + (kb_ ^ swzkey));                \
        }                                                                      \
    }

#define READ_B(dst, c, half)                                                   \
    _Pragma("unroll")                                                          \
    for (int ni_ = 0; ni_ < 4; ++ni_) {                                        \
        _Pragma("unroll")                                                      \
        for (int ks_ = 0; ks_ < 2; ++ks_) {                                    \
            int row_ = (half) * 128 + wcol + ni_ * 16 + l15;                   \
            int kb_ = ks_ * 64 + l4x16;                                        \
            dst[ni_][ks_] = *(const bf16x8*)(sBb + (c) * 32768 + row_ * 128    \
                                             + (kb_ ^ swzkey));                \
        }                                                                      \
    }

#define MMA(ACC, MH, AF, BF) do {                                              \
    __builtin_amdgcn_s_setprio(1);                                             \
    _Pragma("unroll")                                                          \
    for (int ks_ = 0; ks_ < 2; ++ks_) {                                        \
        _Pragma("unroll")                                                      \
        for (int m2_ = 0; m2_ < 2; ++m2_) {                                    \
            _Pragma("unroll")                                                  \
            for (int ni_ = 0; ni_ < 4; ++ni_) {                                \
                ACC[(MH) * 2 + m2_][ni_] =                                     \
                    __builtin_amdgcn_mfma_f32_16x16x32_bf16(                   \
                        AF[m2_][ks_], BF[ni_][ks_], ACC[(MH) * 2 + m2_][ni_],  \
                        0, 0, 0);                                              \
            }                                                                  \
        }                                                                      \
    }                                                                          \
    __builtin_amdgcn_s_setprio(0);                                             \
    __builtin_amdgcn_sched_barrier(0);                                         \
} while (0)

__global__ __launch_bounds__(512, 2) void lstm_gemm_kernel(
    const __bf16* __restrict__ A,    // [8192][1536] pre-swizzled
    const __bf16* __restrict__ Bt,   // [2048][1536] pre-swizzled
    const float* __restrict__ bias,  // [4096]
    const float* __restrict__ c_in,  // [8192][1024]
    float* __restrict__ out_h,       // [8192][1024]
    float* __restrict__ out_c) {     // [8192][1024]
    __shared__ __bf16 sA[2][256][64];   // 64 KiB
    __shared__ __bf16 sB[2][256][64];   // 64 KiB (g rows 0-127, i rows 128-255)

    const int tid  = threadIdx.x;
    const int lane = tid & 63;
    const int wid  = tid >> 6;
    const int wr   = wid & 3;          // 4 wave-rows
    const int wc   = wid >> 2;         // 2 wave-cols

    // XCD-contiguous band map (fix for R4's cross-XCD A broadcast):
    // HW assigns XCD = bid % 8 round-robin, so bid&7 must select the BAND
    // group (A slice), not the panel. XCD x owns bands [4x, 4x+4): its A
    // working set = 3 MB (L2-scale, fetched from HBM once). Panels vary
    // within the XCD; B (6 MB) is the only cross-XCD-shared operand (L3).
    const int bid   = blockIdx.x;              // 0..255
    const int band  = (bid & 7) * 4 + ((bid >> 3) & 3);  // 0..31
    const int panel = bid >> 5;                          // 0..7
    const int brow  = band * 256;
    const int bnp   = panel * 128;

    const int l15    = lane & 15;
    const int l4x16  = (lane >> 4) * 16;
    const int swzkey = (l15 & 7) << 4;
    const int wrow   = wr * 64;
    const int wcol   = wc * 64;

    // staging lane mapping: per wave, LDS dst = uniform base + lane*16
    const int r0 = tid >> 3;           // 0..63
    const int cb = (tid & 7) * 16;     // 0..112

    const char* Ab = (const char*)A;
    const char* Bb = (const char*)Bt;
    char* sAb = (char*)&sA[0][0][0];
    char* sBb = (char*)&sB[0][0][0];

    f32x4 accg[4][4], acci[4][4];
#pragma unroll
    for (int mi = 0; mi < 4; ++mi)
#pragma unroll
        for (int ni = 0; ni < 4; ++ni) {
            accg[mi][ni] = (f32x4){0.f, 0.f, 0.f, 0.f};
            acci[mi][ni] = (f32x4){0.f, 0.f, 0.f, 0.f};
        }

    bf16x8 aF0[2][2], aF1[2][2], bgF[4][2], biF[4][2];

    // prologue: stage tile 0.  Queue order per tile: A0, A1, Bg, Bi.
    STAGE_A(0, 0, 0);
    STAGE_A(0, 1, 0);
    STAGE_B(0, 0, 0);
    STAGE_B(0, 1, 0);

    for (int t = 0; t < NT - 1; ++t) {
        const int c  = t & 1;
        const int nb = c ^ 1;
        // P1: needs A0, A1, Bg of tile t  (oldest 6 of 8 in flight)
        VMW(2); BARRIER;
        READ_A(aF0, c, 0);
        READ_B(bgF, c, 0);
        STAGE_A(nb, 0, t + 1);
        BARRIER; LGKM0;
        MMA(accg, 0, aF0, bgF);
        // P2: no new LDS data needed (A1 landed at P1's wait)
        BARRIER;
        READ_A(aF1, c, 1);
        STAGE_A(nb, 1, t + 1);
        BARRIER; LGKM0;
        MMA(accg, 1, aF1, bgF);
        // P3: needs Bi of tile t  (queue: [Bi(t), A0(t+1), A1(t+1)] = 6)
        VMW(4); BARRIER;
        READ_B(biF, c, 1);
        STAGE_B(nb, 0, t + 1);
        BARRIER; LGKM0;
        MMA(acci, 0, aF0, biF);
        // P4: nothing new needed
        BARRIER;
        STAGE_B(nb, 1, t + 1);
        BARRIER;
        MMA(acci, 1, aF1, biF);
    }
    {   // last tile: exact drains 2 -> 0, no prefetch
        const int c = (NT - 1) & 1;
        VMW(2); BARRIER;
        READ_A(aF0, c, 0);
        READ_B(bgF, c, 0);
        BARRIER; LGKM0;
        MMA(accg, 0, aF0, bgF);
        BARRIER;
        READ_A(aF1, c, 1);
        BARRIER; LGKM0;
        MMA(accg, 1, aF1, bgF);
        VMW(0); BARRIER;
        READ_B(biF, c, 1);
        BARRIER; LGKM0;
        MMA(acci, 0, aF0, biF);
        MMA(acci, 1, aF1, biF);
    }

    // Epilogue: s = sigmoid(i_in); t = tanh(g_in); c_new = s*(t+c); h_new = tanh(c_new)*s
    const int R0 = brow + wrow;
    const int C0 = bnp + wcol;
    const int l4 = lane >> 4;
#pragma unroll
    for (int ni = 0; ni < 4; ++ni) {
        const int col = C0 + ni * 16 + l15;
        const float bg = bias[col];
        const float bi = bias[1024 + col];
#pragma unroll
        for (int mi = 0; mi < 4; ++mi) {
#pragma unroll
            for (int r = 0; r < 4; ++r) {
                const int row = R0 + mi * 16 + l4 * 4 + r;
                const float g_in = accg[mi][ni][r] + bg;
                const float i_in = acci[mi][ni][r] + bi;
                const float s  = 1.0f / (1.0f + __expf(-i_in));
                const float tg = 2.0f / (1.0f + __expf(-2.0f * g_in)) - 1.0f;
                const float cv = c_in[(size_t)row * DH + col];
                const float cn = s * (tg + cv);
                const float hn = (2.0f / (1.0f + __expf(-2.0f * cn)) - 1.0f) * s;
                out_h[(size_t)row * DH + col] = hn;
                out_c[(size_t)row * DH + col] = cn;
            }
        }
    }
}

extern "C" void kernel_launch(void* const* d_in, const int* in_sizes, int n_in,
                              void* d_out, int out_size, void* d_ws, size_t ws_size,
                              hipStream_t stream) {
    const float* x  = (const float*)d_in[0];
    const float* h  = (const float*)d_in[1];
    const float* c  = (const float*)d_in[2];
    const float* Wx = (const float*)d_in[3];
    const float* Wh = (const float*)d_in[4];
    const float* b  = (const float*)d_in[5];

    __bf16* A  = (__bf16*)d_ws;                                     // 25,165,824 B
    __bf16* Bt = (__bf16*)((char*)d_ws + (size_t)BROWS * KTOT * 2); // 6,291,456 B

    float* out_h = (float*)d_out;
    float* out_c = out_h + (size_t)BROWS * DH;

    cvtA_kernel<<<(BROWS * (KTOT / 8)) / 256, 256, 0, stream>>>(x, h, A);
    cvtB_kernel<<<dim3(KTOT / 32, 2048 / 32), dim3(32, 8), 0, stream>>>(Wx, Wh, Bt);
    lstm_gemm_kernel<<<256, 512, 0, stream>>>(A, Bt, b, c, out_h, out_c);
}